// Round 13
// baseline (8158.765 us; speedup 1.0000x reference)
//
#include <hip/hip_runtime.h>

#define NATOMS 300000
#define NCOLS 8
#define VOCABSZ 4096
#define DCOL 32
#define HIDDIM 256
#define NBONDS 320000
#define NGRAPHS 6000
#define NSTEPS 3

constexpr int MP = 300032;             // atoms padded to multiple of 64
constexpr int MTILES64 = MP / 64;      // 4688 gemm blocks

typedef _Float16 f16;
typedef _Float16 f16x4 __attribute__((ext_vector_type(4)));
typedef _Float16 f16x8 __attribute__((ext_vector_type(8)));
typedef float f32x4 __attribute__((ext_vector_type(4)));

constexpr float LO_SCALE = 2048.0f;      // 2^11: keeps lo parts in fp16 NORMAL range
constexpr float INV_LO   = 1.0f / 2048.0f;

__device__ __forceinline__ void split2(float x, f16& h, f16& l) {
    h = (f16)x;
    l = (f16)((x - (float)h) * LO_SCALE);
}

// 16B-unit XOR swizzle (r10: measured ZERO bank conflicts).
__device__ __forceinline__ int swz(int row, int q) {
    return (row * 4 + (q ^ ((row >> 1) & 3))) * 8;
}

// ---------------------------------------------------------------------------
static void* g_pool = nullptr;
__attribute__((constructor)) static void alloc_pool() {
    void* p = nullptr;
    if (hipMalloc(&p, (size_t)1024 * 1024 * 1024) == hipSuccess) {
        hipMemset(p, 0, (size_t)1024 * 1024 * 1024);
        g_pool = p;
    }
}

// ---------------------------------------------------------------------------
__global__ void fill_kernel(float* out, float v, int n) {
    int i = blockIdx.x * blockDim.x + threadIdx.x;
    if (i < n) out[i] = v;
}

// ---------------------------------------------------------------------------
__global__ void build_edges_kernel(const int* __restrict__ bf, int* __restrict__ esrc,
                                   int* __restrict__ nxt, int* head) {
    int e = blockIdx.x * blockDim.x + threadIdx.x;
    if (e >= 2 * NBONDS) return;
    int src, dst;
    if (e < NBONDS) { src = bf[e * 3 + 0]; dst = bf[e * 3 + 1]; }
    else { int i = e - NBONDS; src = bf[i * 3 + 1]; dst = bf[i * 3 + 0]; }
    esrc[e] = src;
    nxt[e] = atomicExch(&head[dst], e);
}

// ---------------------------------------------------------------------------
__global__ void wsplit_kernel(const float* __restrict__ W, f16* __restrict__ Wh,
                              f16* __restrict__ Wl, int n) {
    int i = blockIdx.x * blockDim.x + threadIdx.x;
    if (i >= n) return;
    split2(W[i], Wh[i], Wl[i]);
}

__global__ void bsum_kernel(const float* __restrict__ a, const float* __restrict__ b,
                            float* __restrict__ o) {
    int i = threadIdx.x;
    o[i] = a[i] + b[i];
}

// ---------------------------------------------------------------------------
__global__ void embed_kernel(const int* __restrict__ af, const float* __restrict__ emb,
                             f16* __restrict__ xh, f16* __restrict__ xl) {
    int gid = blockIdx.x * blockDim.x + threadIdx.x;
    int i = gid >> 5, k = gid & 31;
    if (i >= NATOMS) return;
    float s = 0.0f;
#pragma unroll
    for (int c = 0; c < NCOLS; c++) {
        int v = af[i * NCOLS + c];
        int idx = v & (VOCABSZ - 1);
        if (v >= 999999999) idx = 0;
        s += emb[((size_t)c * VOCABSZ + idx) * DCOL + k];
    }
    split2(s, xh[(size_t)i * DCOL + k], xl[(size_t)i * DCOL + k]);
}

// ---------------------------------------------------------------------------
__global__ void agg_kernel(const f16* __restrict__ Ahi, const f16* __restrict__ Alo,
                           f16* __restrict__ Ghi, f16* __restrict__ Glo,
                           const int* __restrict__ head, const int* __restrict__ nxt,
                           const int* __restrict__ esrc) {
    int wid = (blockIdx.x * blockDim.x + threadIdx.x) >> 6;
    int lane = threadIdx.x & 63;
    if (wid >= NATOMS) return;
    float4 sh = make_float4(0.f, 0.f, 0.f, 0.f);
    float4 sl = make_float4(0.f, 0.f, 0.f, 0.f);
    int e = head[wid];
    while (e >= 0) {
        int src = esrc[e];
        const f16x4 vh = *(const f16x4*)(Ahi + (size_t)src * HIDDIM + lane * 4);
        const f16x4 vl = *(const f16x4*)(Alo + (size_t)src * HIDDIM + lane * 4);
        sh.x += (float)vh.x; sh.y += (float)vh.y; sh.z += (float)vh.z; sh.w += (float)vh.w;
        sl.x += (float)vl.x; sl.y += (float)vl.y; sl.z += (float)vl.z; sl.w += (float)vl.w;
        e = nxt[e];
    }
    float4 s;
    s.x = sh.x + sl.x * INV_LO; s.y = sh.y + sl.y * INV_LO;
    s.z = sh.z + sl.z * INV_LO; s.w = sh.w + sl.w * INV_LO;
    f16 h0, l0, h1, l1, h2, l2, h3, l3;
    split2(s.x, h0, l0); split2(s.y, h1, l1);
    split2(s.z, h2, l2); split2(s.w, h3, l3);
    f16x4 oh, ol;
    oh.x = h0; oh.y = h1; oh.z = h2; oh.w = h3;
    ol.x = l0; ol.y = l1; ol.z = l2; ol.w = l3;
    *(f16x4*)(Ghi + (size_t)wid * HIDDIM + lane * 4) = oh;
    *(f16x4*)(Glo + (size_t)wid * HIDDIM + lane * 4) = ol;
}

// ---------------------------------------------------------------------------
// MFMA GEMM (r12 structure) at 4 blocks/CU: LDS 40960 B x 4 = exactly 160 KB,
// VGPR 108 <= 128 cap at (256,4). r10/r11/r12 all sit at hbm_bytes/1.75TB/s
// with 21% occupancy -> double resident blocks to double loads-in-flight.
template <bool HAS_A2, bool RELU, int K>
__global__ __launch_bounds__(256, 4) void mfma_gemm(
    const f16* __restrict__ A1h, const f16* __restrict__ A1l,
    const f16* __restrict__ A2h, const f16* __restrict__ A2l,
    const f16* __restrict__ B1h, const f16* __restrict__ B1l,
    const f16* __restrict__ B2h, const f16* __restrict__ B2l,
    const float* __restrict__ bias,
    f16* __restrict__ Chi, f16* __restrict__ Clo) {
    __shared__ __align__(16) f16 sAh[64 * 32];
    __shared__ __align__(16) f16 sAl[64 * 32];
    __shared__ __align__(16) f16 sBh[256 * 32];
    __shared__ __align__(16) f16 sBl[256 * 32];

    const int t = threadIdx.x;
    const int m0 = blockIdx.x * 64;
    const int lane = t & 63;
    const int wid = t >> 6;     // 0..3
    const int wn = wid * 64;    // wave's column origin
    const int quad = lane >> 4;
    const int l16 = lane & 15;
    const int ra = t >> 2;      // staging row (A) / base row (B)
    const int qa = t & 3;       // staging k-quad

    f32x4 acch[4][4], accl[4][4];   // [mt][nt]
#pragma unroll
    for (int a = 0; a < 4; a++)
#pragma unroll
        for (int b = 0; b < 4; b++) {
            acch[a][b] = (f32x4){0.f, 0.f, 0.f, 0.f};
            accl[a][b] = (f32x4){0.f, 0.f, 0.f, 0.f};
        }

    constexpr int NMAT = HAS_A2 ? 2 : 1;
    constexpr int NST = (K / 32) * NMAT;

    // prefetch registers (named scalars only — r4 lesson: arrays get demoted)
    int4 pAh, pAl, pBh0, pBh1, pBh2, pBh3, pBl0, pBl1, pBl2, pBl3;

#define LOAD_STAGE(S)                                                          \
    {                                                                          \
        const int mat_ = HAS_A2 ? ((S) & 1) : 0;                               \
        const int kb_ = (HAS_A2 ? ((S) >> 1) : (S)) * 32;                      \
        const f16* Ah_ = (mat_ == 0) ? A1h : A2h;                              \
        const f16* Al_ = (mat_ == 0) ? A1l : A2l;                              \
        const f16* Bh_ = (mat_ == 0) ? B1h : B2h;                              \
        const f16* Bl_ = (mat_ == 0) ? B1l : B2l;                              \
        const size_t ao_ = (size_t)(m0 + ra) * K + kb_ + qa * 8;               \
        pAh = *(const int4*)(Ah_ + ao_);                                       \
        pAl = *(const int4*)(Al_ + ao_);                                       \
        const size_t bo_ = (size_t)ra * K + kb_ + qa * 8;                      \
        pBh0 = *(const int4*)(Bh_ + bo_);                                      \
        pBh1 = *(const int4*)(Bh_ + bo_ + (size_t)64 * K);                     \
        pBh2 = *(const int4*)(Bh_ + bo_ + (size_t)128 * K);                    \
        pBh3 = *(const int4*)(Bh_ + bo_ + (size_t)192 * K);                    \
        pBl0 = *(const int4*)(Bl_ + bo_);                                      \
        pBl1 = *(const int4*)(Bl_ + bo_ + (size_t)64 * K);                     \
        pBl2 = *(const int4*)(Bl_ + bo_ + (size_t)128 * K);                    \
        pBl3 = *(const int4*)(Bl_ + bo_ + (size_t)192 * K);                    \
    }

    LOAD_STAGE(0);

    for (int s = 0; s < NST; s++) {
        __syncthreads();
        {
            const int dA = swz(ra, qa);
            *(int4*)(sAh + dA) = pAh;
            *(int4*)(sAl + dA) = pAl;
            const int d0 = swz(ra, qa), d1 = swz(ra + 64, qa);
            const int d2 = swz(ra + 128, qa), d3 = swz(ra + 192, qa);
            *(int4*)(sBh + d0) = pBh0; *(int4*)(sBh + d1) = pBh1;
            *(int4*)(sBh + d2) = pBh2; *(int4*)(sBh + d3) = pBh3;
            *(int4*)(sBl + d0) = pBl0; *(int4*)(sBl + d1) = pBl1;
            *(int4*)(sBl + d2) = pBl2; *(int4*)(sBl + d3) = pBl3;
        }
        __syncthreads();
        if (s + 1 < NST) LOAD_STAGE(s + 1);

        f16x8 fah[4], fal[4];
#pragma unroll
        for (int mt = 0; mt < 4; mt++) {
            const int src = swz(mt * 16 + l16, quad);
            fah[mt] = *(const f16x8*)(sAh + src);
            fal[mt] = *(const f16x8*)(sAl + src);
        }
#pragma unroll
        for (int nt = 0; nt < 4; nt++) {
            const int src = swz(wn + nt * 16 + l16, quad);
            const f16x8 bh = *(const f16x8*)(sBh + src);
            const f16x8 bl = *(const f16x8*)(sBl + src);
#pragma unroll
            for (int mt = 0; mt < 4; mt++) {
                acch[mt][nt] = __builtin_amdgcn_mfma_f32_16x16x32_f16(fah[mt], bh, acch[mt][nt], 0, 0, 0);
                accl[mt][nt] = __builtin_amdgcn_mfma_f32_16x16x32_f16(fah[mt], bl, accl[mt][nt], 0, 0, 0);
                accl[mt][nt] = __builtin_amdgcn_mfma_f32_16x16x32_f16(fal[mt], bh, accl[mt][nt], 0, 0, 0);
            }
        }
    }
#undef LOAD_STAGE

#pragma unroll
    for (int mt = 0; mt < 4; mt++) {
#pragma unroll
        for (int nt = 0; nt < 4; nt++) {
            const int col = wn + nt * 16 + l16;
            const float bv = bias[col];
#pragma unroll
            for (int r = 0; r < 4; r++) {
                const int row = m0 + mt * 16 + quad * 4 + r;
                float v = acch[mt][nt][r] + accl[mt][nt][r] * INV_LO + bv;
                if (RELU) v = fmaxf(v, 0.f);
                f16 hi, lo;
                split2(v, hi, lo);
                Chi[(size_t)row * HIDDIM + col] = hi;
                Clo[(size_t)row * HIDDIM + col] = lo;
            }
        }
    }
}

// ---------------------------------------------------------------------------
// Segment-mean of final h state -> G[6000][256] fp32. (Linearity: the final
// linear layer commutes with the mean — mean(hW^T+b) = mean(h)W^T+b — so the
// 300K-row output GEMM (~350us HBM-bound) is replaced by this + a tiny GEMM.)
__global__ void readout_mean_kernel(const f16* __restrict__ Hhi, const f16* __restrict__ Hlo,
                                    const int* __restrict__ scopes, float* __restrict__ G) {
    int g = blockIdx.x;
    int n = threadIdx.x;
    int start = scopes[g * 2 + 0];
    int len = scopes[g * 2 + 1];
    float s = 0.f;
    for (int j = 0; j < len; j++) {
        size_t o = (size_t)(start + j) * HIDDIM + n;
        s += (float)Hhi[o] + (float)Hlo[o] * INV_LO;
    }
    int d = len > 1 ? len : 1;
    G[(size_t)g * HIDDIM + n] = s / (float)d;
}

// ---------------------------------------------------------------------------
// Tiny fp32 GEMM: out[g][n] = G[g][:] . W_out[n][:] + b_out[n], g<6000.
// Block = 16 graphs x 256 cols; G tile staged in LDS (broadcast reads).
__global__ __launch_bounds__(256) void out_gemm_kernel(
    const float* __restrict__ G, const float* __restrict__ W,
    const float* __restrict__ bias, float* __restrict__ out) {
    __shared__ float sG[16 * 256];
    const int g0 = blockIdx.x * 16;
    const int t = threadIdx.x;
#pragma unroll
    for (int i = 0; i < 16; i++) sG[i * 256 + t] = G[(size_t)(g0 + i) * 256 + t];
    __syncthreads();
    const float bv = bias[t];
    const float* wrow = W + (size_t)t * 256;   // W[n][k] row-major
    float acc[16];
#pragma unroll
    for (int g = 0; g < 16; g++) acc[g] = 0.f;
    for (int k = 0; k < 256; k += 4) {
        const float4 w = *(const float4*)(wrow + k);
#pragma unroll
        for (int g = 0; g < 16; g++) {
            const float4 a = *(const float4*)(sG + g * 256 + k);   // broadcast
            acc[g] = fmaf(a.x, w.x, acc[g]);
            acc[g] = fmaf(a.y, w.y, acc[g]);
            acc[g] = fmaf(a.z, w.z, acc[g]);
            acc[g] = fmaf(a.w, w.w, acc[g]);
        }
    }
#pragma unroll
    for (int g = 0; g < 16; g++) out[(size_t)(g0 + g) * 256 + t] = acc[g] + bv;
}

// ---------------------------------------------------------------------------
extern "C" void kernel_launch(void* const* d_in, const int* in_sizes, int n_in,
                              void* d_out, int out_size, void* d_ws, size_t ws_size,
                              hipStream_t stream) {
    const int* a_features = (const int*)d_in[0];
    const int* b_features = (const int*)d_in[1];
    const int* a_scopes   = (const int*)d_in[2];
    const float* emb      = (const float*)d_in[3];
    const float* W_in     = (const float*)d_in[4];
    const float* b_in     = (const float*)d_in[5];
    const float* W_self   = (const float*)d_in[6];
    const float* b_self   = (const float*)d_in[7];
    const float* W_neigh  = (const float*)d_in[8];
    const float* b_neigh  = (const float*)d_in[9];
    const float* W_out    = (const float*)d_in[10];
    const float* b_out    = (const float*)d_in[11];

    if (g_pool == nullptr) {
        fill_kernel<<<(out_size + 255) / 256, 256, 0, stream>>>(
            (float*)d_out, 77777.0f, out_size);
        return;
    }

    // ---- pool layout (halves) ----
    f16* p = (f16*)g_pool;
    const size_t HB = (size_t)MP * HIDDIM;       // 76,808,192 halves
    f16* hAhi = p;            f16* hAlo = p + HB;
    f16* hBhi = p + 2 * HB;   f16* hBlo = p + 3 * HB;
    f16* hChi = p + 4 * HB;   f16* hClo = p + 5 * HB;
    f16* xhi  = p + 6 * HB;
    f16* xlo  = xhi + (size_t)MP * DCOL;
    f16* Winh = xlo + (size_t)MP * DCOL;
    f16* Winl = Winh + HIDDIM * DCOL;
    f16* Wsh  = Winl + HIDDIM * DCOL;
    f16* Wsl  = Wsh + HIDDIM * HIDDIM;
    f16* Wnh  = Wsl + HIDDIM * HIDDIM;
    f16* Wnl  = Wnh + HIDDIM * HIDDIM;
    float* Gmean = (float*)(Wnl + HIDDIM * HIDDIM);        // [6000][256] fp32
    float* bsum  = Gmean + (size_t)NGRAPHS * HIDDIM;
    int* esrc = (int*)(bsum + HIDDIM);
    int* nxt  = esrc + 2 * NBONDS;
    int* head = nxt + 2 * NBONDS;

    constexpr int NPAD = MP - NATOMS;            // 32 pad rows

    // ---- setup (identical every launch) ----
    hipMemsetAsync(head, 0xFF, (size_t)MP * sizeof(int), stream);
    build_edges_kernel<<<(2 * NBONDS + 255) / 256, 256, 0, stream>>>(b_features, esrc, nxt, head);
    wsplit_kernel<<<(HIDDIM * DCOL + 255) / 256, 256, 0, stream>>>(W_in, Winh, Winl, HIDDIM * DCOL);
    wsplit_kernel<<<(HIDDIM * HIDDIM + 255) / 256, 256, 0, stream>>>(W_self, Wsh, Wsl, HIDDIM * HIDDIM);
    wsplit_kernel<<<(HIDDIM * HIDDIM + 255) / 256, 256, 0, stream>>>(W_neigh, Wnh, Wnl, HIDDIM * HIDDIM);
    bsum_kernel<<<1, HIDDIM, 0, stream>>>(b_self, b_neigh, bsum);

    // Zero padding rows of every pair buffer (pool is persistent).
    constexpr int PADF = NPAD * HIDDIM / 2;      // halves -> floats
    fill_kernel<<<(PADF + 255) / 256, 256, 0, stream>>>((float*)(hAhi + (size_t)NATOMS * HIDDIM), 0.f, PADF);
    fill_kernel<<<(PADF + 255) / 256, 256, 0, stream>>>((float*)(hAlo + (size_t)NATOMS * HIDDIM), 0.f, PADF);
    fill_kernel<<<(PADF + 255) / 256, 256, 0, stream>>>((float*)(hBhi + (size_t)NATOMS * HIDDIM), 0.f, PADF);
    fill_kernel<<<(PADF + 255) / 256, 256, 0, stream>>>((float*)(hBlo + (size_t)NATOMS * HIDDIM), 0.f, PADF);
    fill_kernel<<<(PADF + 255) / 256, 256, 0, stream>>>((float*)(hChi + (size_t)NATOMS * HIDDIM), 0.f, PADF);
    fill_kernel<<<(PADF + 255) / 256, 256, 0, stream>>>((float*)(hClo + (size_t)NATOMS * HIDDIM), 0.f, PADF);
    constexpr int PADX = NPAD * DCOL / 2;
    fill_kernel<<<(PADX + 255) / 256, 256, 0, stream>>>((float*)(xhi + (size_t)NATOMS * DCOL), 0.f, PADX);
    fill_kernel<<<(PADX + 255) / 256, 256, 0, stream>>>((float*)(xlo + (size_t)NATOMS * DCOL), 0.f, PADX);

    // ---- embedding + input linear -> h (pair bufA) ----
    embed_kernel<<<(NATOMS * DCOL + 255) / 256, 256, 0, stream>>>(a_features, emb, xhi, xlo);
    mfma_gemm<false, false, DCOL><<<MTILES64, 256, 0, stream>>>(
        xhi, xlo, nullptr, nullptr, Winh, Winl, nullptr, nullptr, b_in, hAhi, hAlo);

    // ---- 3 message-passing steps with rotating pair buffers ----
    f16 *h_hi = hAhi, *h_lo = hAlo;
    f16 *g_hi = hBhi, *g_lo = hBlo;
    f16 *n_hi = hChi, *n_lo = hClo;
    for (int s = 0; s < NSTEPS; s++) {
        agg_kernel<<<NATOMS / 4, 256, 0, stream>>>(h_hi, h_lo, g_hi, g_lo, head, nxt, esrc);
        mfma_gemm<true, true, HIDDIM><<<MTILES64, 256, 0, stream>>>(
            h_hi, h_lo, g_hi, g_lo, Wsh, Wsl, Wnh, Wnl, bsum, n_hi, n_lo);
        f16* t1 = h_hi; f16* t2 = h_lo;
        h_hi = n_hi; h_lo = n_lo;
        n_hi = g_hi; n_lo = g_lo;
        g_hi = t1;   g_lo = t2;
    }

    // ---- mean first (linearity), then tiny output linear ----
    readout_mean_kernel<<<NGRAPHS, 256, 0, stream>>>(h_hi, h_lo, a_scopes, Gmean);
    out_gemm_kernel<<<NGRAPHS / 16, 256, 0, stream>>>(Gmean, W_out, b_out, (float*)d_out);
}

// Round 14
// 2042.318 us; speedup vs baseline: 3.9949x; 3.9949x over previous
//
#include <hip/hip_runtime.h>

#define NATOMS 300000
#define NCOLS 8
#define VOCABSZ 4096
#define DCOL 32
#define HIDDIM 256
#define NBONDS 320000
#define NGRAPHS 6000
#define NSTEPS 3

constexpr int MP = 300032;             // atoms padded to multiple of 64
constexpr int MTILES64 = MP / 64;      // 4688 gemm blocks

typedef _Float16 f16;
typedef _Float16 f16x4 __attribute__((ext_vector_type(4)));
typedef _Float16 f16x8 __attribute__((ext_vector_type(8)));
typedef float f32x4 __attribute__((ext_vector_type(4)));

constexpr float LO_SCALE = 2048.0f;      // 2^11: keeps lo parts in fp16 NORMAL range
constexpr float INV_LO   = 1.0f / 2048.0f;

__device__ __forceinline__ void split2(float x, f16& h, f16& l) {
    h = (f16)x;
    l = (f16)((x - (float)h) * LO_SCALE);
}

// 16B-unit XOR swizzle (r10: measured ZERO bank conflicts).
__device__ __forceinline__ int swz(int row, int q) {
    return (row * 4 + (q ^ ((row >> 1) & 3))) * 8;
}

// ---------------------------------------------------------------------------
static void* g_pool = nullptr;
__attribute__((constructor)) static void alloc_pool() {
    void* p = nullptr;
    if (hipMalloc(&p, (size_t)1024 * 1024 * 1024) == hipSuccess) {
        hipMemset(p, 0, (size_t)1024 * 1024 * 1024);
        g_pool = p;
    }
}

// ---------------------------------------------------------------------------
__global__ void fill_kernel(float* out, float v, int n) {
    int i = blockIdx.x * blockDim.x + threadIdx.x;
    if (i < n) out[i] = v;
}

// ---------------------------------------------------------------------------
__global__ void build_edges_kernel(const int* __restrict__ bf, int* __restrict__ esrc,
                                   int* __restrict__ nxt, int* head) {
    int e = blockIdx.x * blockDim.x + threadIdx.x;
    if (e >= 2 * NBONDS) return;
    int src, dst;
    if (e < NBONDS) { src = bf[e * 3 + 0]; dst = bf[e * 3 + 1]; }
    else { int i = e - NBONDS; src = bf[i * 3 + 1]; dst = bf[i * 3 + 0]; }
    esrc[e] = src;
    nxt[e] = atomicExch(&head[dst], e);
}

// ---------------------------------------------------------------------------
__global__ void wsplit_kernel(const float* __restrict__ W, f16* __restrict__ Wh,
                              f16* __restrict__ Wl, int n) {
    int i = blockIdx.x * blockDim.x + threadIdx.x;
    if (i >= n) return;
    split2(W[i], Wh[i], Wl[i]);
}

__global__ void bsum_kernel(const float* __restrict__ a, const float* __restrict__ b,
                            float* __restrict__ o) {
    int i = threadIdx.x;
    o[i] = a[i] + b[i];
}

// ---------------------------------------------------------------------------
__global__ void embed_kernel(const int* __restrict__ af, const float* __restrict__ emb,
                             f16* __restrict__ xh, f16* __restrict__ xl) {
    int gid = blockIdx.x * blockDim.x + threadIdx.x;
    int i = gid >> 5, k = gid & 31;
    if (i >= NATOMS) return;
    float s = 0.0f;
#pragma unroll
    for (int c = 0; c < NCOLS; c++) {
        int v = af[i * NCOLS + c];
        int idx = v & (VOCABSZ - 1);
        if (v >= 999999999) idx = 0;
        s += emb[((size_t)c * VOCABSZ + idx) * DCOL + k];
    }
    split2(s, xh[(size_t)i * DCOL + k], xl[(size_t)i * DCOL + k]);
}

// ---------------------------------------------------------------------------
__global__ void agg_kernel(const f16* __restrict__ Ahi, const f16* __restrict__ Alo,
                           f16* __restrict__ Ghi, f16* __restrict__ Glo,
                           const int* __restrict__ head, const int* __restrict__ nxt,
                           const int* __restrict__ esrc) {
    int wid = (blockIdx.x * blockDim.x + threadIdx.x) >> 6;
    int lane = threadIdx.x & 63;
    if (wid >= NATOMS) return;
    float4 sh = make_float4(0.f, 0.f, 0.f, 0.f);
    float4 sl = make_float4(0.f, 0.f, 0.f, 0.f);
    int e = head[wid];
    while (e >= 0) {
        int src = esrc[e];
        const f16x4 vh = *(const f16x4*)(Ahi + (size_t)src * HIDDIM + lane * 4);
        const f16x4 vl = *(const f16x4*)(Alo + (size_t)src * HIDDIM + lane * 4);
        sh.x += (float)vh.x; sh.y += (float)vh.y; sh.z += (float)vh.z; sh.w += (float)vh.w;
        sl.x += (float)vl.x; sl.y += (float)vl.y; sl.z += (float)vl.z; sl.w += (float)vl.w;
        e = nxt[e];
    }
    float4 s;
    s.x = sh.x + sl.x * INV_LO; s.y = sh.y + sl.y * INV_LO;
    s.z = sh.z + sl.z * INV_LO; s.w = sh.w + sl.w * INV_LO;
    f16 h0, l0, h1, l1, h2, l2, h3, l3;
    split2(s.x, h0, l0); split2(s.y, h1, l1);
    split2(s.z, h2, l2); split2(s.w, h3, l3);
    f16x4 oh, ol;
    oh.x = h0; oh.y = h1; oh.z = h2; oh.w = h3;
    ol.x = l0; ol.y = l1; ol.z = l2; ol.w = l3;
    *(f16x4*)(Ghi + (size_t)wid * HIDDIM + lane * 4) = oh;
    *(f16x4*)(Glo + (size_t)wid * HIDDIM + lane * 4) = ol;
}

// ---------------------------------------------------------------------------
// MFMA GEMM — r12 proven config (365us fused, zero conflicts, no spills).
// __launch_bounds__(256,2) is STRUCTURAL: per-wave budget = ~108 arch VGPR +
// 128 acc (unified file on gfx950) ≈ 236; 2 waves/SIMD = 472 <= 512. (256,4)
// capped the wave at 128 total -> 6 GB spill traffic (r13). Do not raise.
template <bool HAS_A2, bool RELU, int K>
__global__ __launch_bounds__(256, 2) void mfma_gemm(
    const f16* __restrict__ A1h, const f16* __restrict__ A1l,
    const f16* __restrict__ A2h, const f16* __restrict__ A2l,
    const f16* __restrict__ B1h, const f16* __restrict__ B1l,
    const f16* __restrict__ B2h, const f16* __restrict__ B2l,
    const float* __restrict__ bias,
    f16* __restrict__ Chi, f16* __restrict__ Clo) {
    __shared__ __align__(16) f16 sAh[64 * 32];
    __shared__ __align__(16) f16 sAl[64 * 32];
    __shared__ __align__(16) f16 sBh[256 * 32];
    __shared__ __align__(16) f16 sBl[256 * 32];

    const int t = threadIdx.x;
    const int m0 = blockIdx.x * 64;
    const int lane = t & 63;
    const int wid = t >> 6;     // 0..3
    const int wn = wid * 64;    // wave's column origin
    const int quad = lane >> 4;
    const int l16 = lane & 15;
    const int ra = t >> 2;      // staging row (A) / base row (B)
    const int qa = t & 3;       // staging k-quad

    f32x4 acch[4][4], accl[4][4];   // [mt][nt]
#pragma unroll
    for (int a = 0; a < 4; a++)
#pragma unroll
        for (int b = 0; b < 4; b++) {
            acch[a][b] = (f32x4){0.f, 0.f, 0.f, 0.f};
            accl[a][b] = (f32x4){0.f, 0.f, 0.f, 0.f};
        }

    constexpr int NMAT = HAS_A2 ? 2 : 1;
    constexpr int NST = (K / 32) * NMAT;

    // prefetch registers (named scalars only — r4 lesson: arrays get demoted)
    int4 pAh, pAl, pBh0, pBh1, pBh2, pBh3, pBl0, pBl1, pBl2, pBl3;

#define LOAD_STAGE(S)                                                          \
    {                                                                          \
        const int mat_ = HAS_A2 ? ((S) & 1) : 0;                               \
        const int kb_ = (HAS_A2 ? ((S) >> 1) : (S)) * 32;                      \
        const f16* Ah_ = (mat_ == 0) ? A1h : A2h;                              \
        const f16* Al_ = (mat_ == 0) ? A1l : A2l;                              \
        const f16* Bh_ = (mat_ == 0) ? B1h : B2h;                              \
        const f16* Bl_ = (mat_ == 0) ? B1l : B2l;                              \
        const size_t ao_ = (size_t)(m0 + ra) * K + kb_ + qa * 8;               \
        pAh = *(const int4*)(Ah_ + ao_);                                       \
        pAl = *(const int4*)(Al_ + ao_);                                       \
        const size_t bo_ = (size_t)ra * K + kb_ + qa * 8;                      \
        pBh0 = *(const int4*)(Bh_ + bo_);                                      \
        pBh1 = *(const int4*)(Bh_ + bo_ + (size_t)64 * K);                     \
        pBh2 = *(const int4*)(Bh_ + bo_ + (size_t)128 * K);                    \
        pBh3 = *(const int4*)(Bh_ + bo_ + (size_t)192 * K);                    \
        pBl0 = *(const int4*)(Bl_ + bo_);                                      \
        pBl1 = *(const int4*)(Bl_ + bo_ + (size_t)64 * K);                     \
        pBl2 = *(const int4*)(Bl_ + bo_ + (size_t)128 * K);                    \
        pBl3 = *(const int4*)(Bl_ + bo_ + (size_t)192 * K);                    \
    }

    LOAD_STAGE(0);

    for (int s = 0; s < NST; s++) {
        __syncthreads();
        {
            const int dA = swz(ra, qa);
            *(int4*)(sAh + dA) = pAh;
            *(int4*)(sAl + dA) = pAl;
            const int d0 = swz(ra, qa), d1 = swz(ra + 64, qa);
            const int d2 = swz(ra + 128, qa), d3 = swz(ra + 192, qa);
            *(int4*)(sBh + d0) = pBh0; *(int4*)(sBh + d1) = pBh1;
            *(int4*)(sBh + d2) = pBh2; *(int4*)(sBh + d3) = pBh3;
            *(int4*)(sBl + d0) = pBl0; *(int4*)(sBl + d1) = pBl1;
            *(int4*)(sBl + d2) = pBl2; *(int4*)(sBl + d3) = pBl3;
        }
        __syncthreads();
        if (s + 1 < NST) LOAD_STAGE(s + 1);

        f16x8 fah[4], fal[4];
#pragma unroll
        for (int mt = 0; mt < 4; mt++) {
            const int src = swz(mt * 16 + l16, quad);
            fah[mt] = *(const f16x8*)(sAh + src);
            fal[mt] = *(const f16x8*)(sAl + src);
        }
#pragma unroll
        for (int nt = 0; nt < 4; nt++) {
            const int src = swz(wn + nt * 16 + l16, quad);
            const f16x8 bh = *(const f16x8*)(sBh + src);
            const f16x8 bl = *(const f16x8*)(sBl + src);
#pragma unroll
            for (int mt = 0; mt < 4; mt++) {
                acch[mt][nt] = __builtin_amdgcn_mfma_f32_16x16x32_f16(fah[mt], bh, acch[mt][nt], 0, 0, 0);
                accl[mt][nt] = __builtin_amdgcn_mfma_f32_16x16x32_f16(fah[mt], bl, accl[mt][nt], 0, 0, 0);
                accl[mt][nt] = __builtin_amdgcn_mfma_f32_16x16x32_f16(fal[mt], bh, accl[mt][nt], 0, 0, 0);
            }
        }
    }
#undef LOAD_STAGE

#pragma unroll
    for (int mt = 0; mt < 4; mt++) {
#pragma unroll
        for (int nt = 0; nt < 4; nt++) {
            const int col = wn + nt * 16 + l16;
            const float bv = bias[col];
#pragma unroll
            for (int r = 0; r < 4; r++) {
                const int row = m0 + mt * 16 + quad * 4 + r;
                float v = acch[mt][nt][r] + accl[mt][nt][r] * INV_LO + bv;
                if (RELU) v = fmaxf(v, 0.f);
                f16 hi, lo;
                split2(v, hi, lo);
                Chi[(size_t)row * HIDDIM + col] = hi;
                Clo[(size_t)row * HIDDIM + col] = lo;
            }
        }
    }
}

// ---------------------------------------------------------------------------
// Segment-mean of final h state -> G[6000][256] fp32. Linearity: the final
// linear commutes with the mean — mean(hW^T+b) = mean(h)W^T+b — so the
// 300K-row output GEMM is replaced by this + a 6000-row GEMM. (r13: verified,
// absmax improved to 9.77e-4.)
__global__ void readout_mean_kernel(const f16* __restrict__ Hhi, const f16* __restrict__ Hlo,
                                    const int* __restrict__ scopes, float* __restrict__ G) {
    int g = blockIdx.x;
    int n = threadIdx.x;
    int start = scopes[g * 2 + 0];
    int len = scopes[g * 2 + 1];
    float s = 0.f;
    for (int j = 0; j < len; j++) {
        size_t o = (size_t)(start + j) * HIDDIM + n;
        s += (float)Hhi[o] + (float)Hlo[o] * INV_LO;
    }
    int d = len > 1 ? len : 1;
    G[(size_t)g * HIDDIM + n] = s / (float)d;
}

// ---------------------------------------------------------------------------
// Tiny fp32 GEMM: out[g][n] = G[g][:] . W_out[n][:] + b_out[n], g<6000.
__global__ __launch_bounds__(256) void out_gemm_kernel(
    const float* __restrict__ G, const float* __restrict__ W,
    const float* __restrict__ bias, float* __restrict__ out) {
    __shared__ float sG[16 * 256];
    const int g0 = blockIdx.x * 16;
    const int t = threadIdx.x;
#pragma unroll
    for (int i = 0; i < 16; i++) sG[i * 256 + t] = G[(size_t)(g0 + i) * 256 + t];
    __syncthreads();
    const float bv = bias[t];
    const float* wrow = W + (size_t)t * 256;   // W[n][k] row-major
    float acc[16];
#pragma unroll
    for (int g = 0; g < 16; g++) acc[g] = 0.f;
    for (int k = 0; k < 256; k += 4) {
        const float4 w = *(const float4*)(wrow + k);
#pragma unroll
        for (int g = 0; g < 16; g++) {
            const float4 a = *(const float4*)(sG + g * 256 + k);   // broadcast
            acc[g] = fmaf(a.x, w.x, acc[g]);
            acc[g] = fmaf(a.y, w.y, acc[g]);
            acc[g] = fmaf(a.z, w.z, acc[g]);
            acc[g] = fmaf(a.w, w.w, acc[g]);
        }
    }
#pragma unroll
    for (int g = 0; g < 16; g++) out[(size_t)(g0 + g) * 256 + t] = acc[g] + bv;
}

// ---------------------------------------------------------------------------
extern "C" void kernel_launch(void* const* d_in, const int* in_sizes, int n_in,
                              void* d_out, int out_size, void* d_ws, size_t ws_size,
                              hipStream_t stream) {
    const int* a_features = (const int*)d_in[0];
    const int* b_features = (const int*)d_in[1];
    const int* a_scopes   = (const int*)d_in[2];
    const float* emb      = (const float*)d_in[3];
    const float* W_in     = (const float*)d_in[4];
    const float* b_in     = (const float*)d_in[5];
    const float* W_self   = (const float*)d_in[6];
    const float* b_self   = (const float*)d_in[7];
    const float* W_neigh  = (const float*)d_in[8];
    const float* b_neigh  = (const float*)d_in[9];
    const float* W_out    = (const float*)d_in[10];
    const float* b_out    = (const float*)d_in[11];

    if (g_pool == nullptr) {
        fill_kernel<<<(out_size + 255) / 256, 256, 0, stream>>>(
            (float*)d_out, 77777.0f, out_size);
        return;
    }

    // ---- pool layout (halves) ----
    f16* p = (f16*)g_pool;
    const size_t HB = (size_t)MP * HIDDIM;       // 76,808,192 halves
    f16* hAhi = p;            f16* hAlo = p + HB;
    f16* hBhi = p + 2 * HB;   f16* hBlo = p + 3 * HB;
    f16* hChi = p + 4 * HB;   f16* hClo = p + 5 * HB;
    f16* xhi  = p + 6 * HB;
    f16* xlo  = xhi + (size_t)MP * DCOL;
    f16* Winh = xlo + (size_t)MP * DCOL;
    f16* Winl = Winh + HIDDIM * DCOL;
    f16* Wsh  = Winl + HIDDIM * DCOL;
    f16* Wsl  = Wsh + HIDDIM * HIDDIM;
    f16* Wnh  = Wsl + HIDDIM * HIDDIM;
    f16* Wnl  = Wnh + HIDDIM * HIDDIM;
    float* Gmean = (float*)(Wnl + HIDDIM * HIDDIM);        // [6000][256] fp32
    float* bsum  = Gmean + (size_t)NGRAPHS * HIDDIM;
    int* esrc = (int*)(bsum + HIDDIM);
    int* nxt  = esrc + 2 * NBONDS;
    int* head = nxt + 2 * NBONDS;

    constexpr int NPAD = MP - NATOMS;            // 32 pad rows

    // ---- setup (identical every launch) ----
    hipMemsetAsync(head, 0xFF, (size_t)MP * sizeof(int), stream);
    build_edges_kernel<<<(2 * NBONDS + 255) / 256, 256, 0, stream>>>(b_features, esrc, nxt, head);
    wsplit_kernel<<<(HIDDIM * DCOL + 255) / 256, 256, 0, stream>>>(W_in, Winh, Winl, HIDDIM * DCOL);
    wsplit_kernel<<<(HIDDIM * HIDDIM + 255) / 256, 256, 0, stream>>>(W_self, Wsh, Wsl, HIDDIM * HIDDIM);
    wsplit_kernel<<<(HIDDIM * HIDDIM + 255) / 256, 256, 0, stream>>>(W_neigh, Wnh, Wnl, HIDDIM * HIDDIM);
    bsum_kernel<<<1, HIDDIM, 0, stream>>>(b_self, b_neigh, bsum);

    // Zero padding rows of every pair buffer (pool is persistent).
    constexpr int PADF = NPAD * HIDDIM / 2;      // halves -> floats
    fill_kernel<<<(PADF + 255) / 256, 256, 0, stream>>>((float*)(hAhi + (size_t)NATOMS * HIDDIM), 0.f, PADF);
    fill_kernel<<<(PADF + 255) / 256, 256, 0, stream>>>((float*)(hAlo + (size_t)NATOMS * HIDDIM), 0.f, PADF);
    fill_kernel<<<(PADF + 255) / 256, 256, 0, stream>>>((float*)(hBhi + (size_t)NATOMS * HIDDIM), 0.f, PADF);
    fill_kernel<<<(PADF + 255) / 256, 256, 0, stream>>>((float*)(hBlo + (size_t)NATOMS * HIDDIM), 0.f, PADF);
    fill_kernel<<<(PADF + 255) / 256, 256, 0, stream>>>((float*)(hChi + (size_t)NATOMS * HIDDIM), 0.f, PADF);
    fill_kernel<<<(PADF + 255) / 256, 256, 0, stream>>>((float*)(hClo + (size_t)NATOMS * HIDDIM), 0.f, PADF);
    constexpr int PADX = NPAD * DCOL / 2;
    fill_kernel<<<(PADX + 255) / 256, 256, 0, stream>>>((float*)(xhi + (size_t)NATOMS * DCOL), 0.f, PADX);
    fill_kernel<<<(PADX + 255) / 256, 256, 0, stream>>>((float*)(xlo + (size_t)NATOMS * DCOL), 0.f, PADX);

    // ---- embedding + input linear -> h (pair bufA) ----
    embed_kernel<<<(NATOMS * DCOL + 255) / 256, 256, 0, stream>>>(a_features, emb, xhi, xlo);
    mfma_gemm<false, false, DCOL><<<MTILES64, 256, 0, stream>>>(
        xhi, xlo, nullptr, nullptr, Winh, Winl, nullptr, nullptr, b_in, hAhi, hAlo);

    // ---- 3 message-passing steps with rotating pair buffers ----
    f16 *h_hi = hAhi, *h_lo = hAlo;
    f16 *g_hi = hBhi, *g_lo = hBlo;
    f16 *n_hi = hChi, *n_lo = hClo;
    for (int s = 0; s < NSTEPS; s++) {
        agg_kernel<<<NATOMS / 4, 256, 0, stream>>>(h_hi, h_lo, g_hi, g_lo, head, nxt, esrc);
        mfma_gemm<true, true, HIDDIM><<<MTILES64, 256, 0, stream>>>(
            h_hi, h_lo, g_hi, g_lo, Wsh, Wsl, Wnh, Wnl, bsum, n_hi, n_lo);
        f16* t1 = h_hi; f16* t2 = h_lo;
        h_hi = n_hi; h_lo = n_lo;
        n_hi = g_hi; n_lo = g_lo;
        g_hi = t1;   g_lo = t2;
    }

    // ---- mean first (linearity), then tiny output linear ----
    readout_mean_kernel<<<NGRAPHS, 256, 0, stream>>>(h_hi, h_lo, a_scopes, Gmean);
    out_gemm_kernel<<<NGRAPHS / 16, 256, 0, stream>>>(Gmean, W_out, b_out, (float*)d_out);
}